// Round 2
// baseline (184.709 us; speedup 1.0000x reference)
//
#include <hip/hip_runtime.h>
#include <cstdint>

typedef __bf16 bf16;
typedef __bf16 bf16x4 __attribute__((ext_vector_type(4)));
typedef __bf16 bf16x8 __attribute__((ext_vector_type(8)));
typedef float floatx4 __attribute__((ext_vector_type(4)));
typedef float f32x16 __attribute__((ext_vector_type(16)));
typedef unsigned int uint2v __attribute__((ext_vector_type(2)));
typedef unsigned int uint4v __attribute__((ext_vector_type(4)));

typedef const __attribute__((address_space(1))) void* as1_cvptr;
typedef __attribute__((address_space(3))) void* as3_vptr;

__device__ __forceinline__ void gl_lds16(const void* g, void* l) {
  __builtin_amdgcn_global_load_lds((as1_cvptr)(uintptr_t)g,
                                   (as3_vptr)(uint32_t)(uintptr_t)l, 16, 0, 0);
}

#define EMBED 1024
#define SEQ 2048
#define NH 16
#define DH 64
// softmax scale folded into Q at projection time: 0.125 * log2(e)
#define QSCALE 0.18033688f

// pack two f32 -> one u32 of 2 bf16 (compiler fuses to v_cvt_pk_bf16_f32)
__device__ __forceinline__ unsigned pk_bf16(float a, float b) {
  unsigned short ua = __builtin_bit_cast(unsigned short, (bf16)a);
  unsigned short ub = __builtin_bit_cast(unsigned short, (bf16)b);
  return (unsigned)ua | ((unsigned)ub << 16);
}

// ---------------------------------------------------------------------------
// Kernel A: prep — grid (256,4). z<3: transpose+downcast W z; z=3: x->bf16.
// ---------------------------------------------------------------------------
__global__ __launch_bounds__(256) void prep(
    const float* __restrict__ x, const float* __restrict__ Wq,
    const float* __restrict__ Wk, const float* __restrict__ Wv,
    bf16* __restrict__ xb, bf16* __restrict__ Wqt,
    bf16* __restrict__ Wkt, bf16* __restrict__ Wvt) {
  __shared__ __align__(16) bf16 tile[64][72];
  int z = blockIdx.y;
  int t = threadIdx.x;
  if (z == 3) {
    size_t base = ((size_t)blockIdx.x * 256 + t) * 8;
#pragma unroll
    for (int it = 0; it < 8; ++it) {
      size_t i = base + (size_t)it * (256 * 256 * 8);
      floatx4 a = *(const floatx4*)(x + i);
      floatx4 bv = *(const floatx4*)(x + i + 4);
      bf16x8 o;
#pragma unroll
      for (int j = 0; j < 4; ++j) { o[j] = (bf16)a[j]; o[4 + j] = (bf16)bv[j]; }
      *(bf16x8*)(xb + i) = o;
    }
    return;
  }
  const float* W = (z == 0) ? Wq : (z == 1) ? Wk : Wv;
  bf16* Wt = (z == 0) ? Wqt : (z == 1) ? Wkt : Wvt;
  int k0 = (blockIdx.x >> 4) * 64, n0 = (blockIdx.x & 15) * 64;
  int r = t >> 3, c = (t & 7) * 8;
#pragma unroll
  for (int half = 0; half < 2; ++half) {
    const float* src = &W[(size_t)(k0 + r + half * 32) * EMBED + n0 + c];
    floatx4 f0 = *(const floatx4*)src;
    floatx4 f1 = *(const floatx4*)(src + 4);
    bf16x8 o;
#pragma unroll
    for (int j = 0; j < 4; ++j) { o[j] = (bf16)f0[j]; o[4 + j] = (bf16)f1[j]; }
    *(bf16x8*)&tile[r + half * 32][c] = o;
  }
  __syncthreads();
#pragma unroll
  for (int p = 0; p < 2; ++p) {
    int nn = (t >> 3) + p * 32, kk = (t & 7) * 8;
    bf16x8 v;
#pragma unroll
    for (int i = 0; i < 8; ++i) v[i] = tile[kk + i][nn];
    *(bf16x8*)&Wt[(size_t)(n0 + nn) * EMBED + k0 + kk] = v;
  }
}

// ---------------------------------------------------------------------------
// Kernel B: fused QKV projection (unchanged this round; isolate flash delta).
// ---------------------------------------------------------------------------
__global__ __launch_bounds__(256) void qkv3(
    const bf16* __restrict__ Xb, const bf16* __restrict__ Wqt,
    const bf16* __restrict__ Wkt, const bf16* __restrict__ Wvt,
    bf16* __restrict__ qo, bf16* __restrict__ ko, bf16* __restrict__ vto) {
  __shared__ __align__(16) bf16 As[128 * 32];
  __shared__ __align__(16) bf16 Bs[128 * 32];

  int gid = blockIdx.x;
  int z = gid % 3;
  int rem = gid / 3;
  int bxx = rem & 7, byy = rem >> 3;

  const bf16* Wt = (z == 0) ? Wqt : (z == 1) ? Wkt : Wvt;
  bf16* out = (z == 0) ? qo : (z == 1) ? ko : vto;
  int m0 = (z == 2 ? bxx : byy) * 128;
  int n0 = (z == 2 ? byy : bxx) * 128;
  const bf16* Asrc = (z == 2) ? Wt : Xb;
  const bf16* Bsrc = (z == 2) ? Xb : Wt;
  float oscale = (z == 0) ? QSCALE : 1.0f;

  int t = threadIdx.x;
  int w = t >> 6, lane = t & 63, ln = lane & 15, quad = lane >> 4;
  int wm = (w >> 1) * 64, wn = (w & 1) * 64;

  floatx4 acc[4][4];
#pragma unroll
  for (int i = 0; i < 4; ++i)
#pragma unroll
    for (int j = 0; j < 4; ++j) acc[i][j] = floatx4{0.f, 0.f, 0.f, 0.f};

  int sr = t >> 2, sc = (t & 3) * 8;
  const bf16* ag = Asrc + (size_t)(m0 + sr) * EMBED + sc;
  const bf16* bg = Bsrc + (size_t)(n0 + sr) * EMBED + sc;
  bf16* al = As + sr * 32 + sc;
  bf16* bl = Bs + sr * 32 + sc;

  for (int k0 = 0; k0 < EMBED; k0 += 32) {
    __syncthreads();
    gl_lds16(ag + k0, al);
    gl_lds16(ag + k0 + (size_t)64 * EMBED, al + 64 * 32);
    gl_lds16(bg + k0, bl);
    gl_lds16(bg + k0 + (size_t)64 * EMBED, bl + 64 * 32);
    __syncthreads();

    bf16x8 afr[4], bfr[4];
#pragma unroll
    for (int i = 0; i < 4; ++i)
      afr[i] = *(const bf16x8*)&As[(wm + i * 16 + ln) * 32 + quad * 8];
#pragma unroll
    for (int j = 0; j < 4; ++j)
      bfr[j] = *(const bf16x8*)&Bs[(wn + j * 16 + ln) * 32 + quad * 8];
#pragma unroll
    for (int i = 0; i < 4; ++i)
#pragma unroll
      for (int j = 0; j < 4; ++j)
        acc[i][j] =
            __builtin_amdgcn_mfma_f32_16x16x32_bf16(afr[i], bfr[j], acc[i][j], 0, 0, 0);
  }

#pragma unroll
  for (int i = 0; i < 4; ++i) {
#pragma unroll
    for (int r = 0; r < 4; ++r) {
      int row = m0 + wm + i * 16 + quad * 4 + r;
#pragma unroll
      for (int j = 0; j < 4; ++j) {
        int col = n0 + wn + j * 16 + ln;
        float v = acc[i][j][r] * oscale;
        size_t dst;
        if (z != 2) {
          int b = row >> 11, ns = row & 2047, h = col >> 6, d = col & 63;
          dst = ((size_t)((b * NH + h) * SEQ + ns)) * DH + d;
        } else {
          int h = row >> 6, d = row & 63, b = col >> 11, ns = col & 2047;
          dst = ((size_t)((b * NH + h) * DH + d)) * SEQ + ns;
        }
        out[dst] = (bf16)v;
      }
    }
  }
}

// ---------------------------------------------------------------------------
// Kernel C: flash v5 — 32x32x16 MFMA, 32 q/wave, in-register P via
// permlane32_swap (T12), 4-way split-K (exact for no-max softmax),
// double-buffered K/V LDS (1 barrier/tile), coalesced f32x4 epilogue.
// 16 waves = 4 q-groups x 4 key-splits; each wave: 32 q x 512 keys.
// LDS 144KB -> 1 block/CU, 16 waves/CU, VGPR<=128 (4 waves/SIMD).
// Layouts (HW-verified, guide §3): 32x32x16 C/D: col=lane&31,
// row=(r&3)+8(r>>2)+4(lane>>5); A/B: row/col=lane&31, k=(lane>>5)*8+j.
// ---------------------------------------------------------------------------
__global__ __launch_bounds__(1024, 4) void flash(
    const bf16* __restrict__ Qg, const bf16* __restrict__ Kg,
    const bf16* __restrict__ Vtg, float* __restrict__ Og) {
  // Ks[2 buf][4 split][64 key][72] | Vs[2][4][64 d][72]  = 147456 B
  __shared__ __align__(16) char smem[147456];
  bf16* Ks = (bf16*)smem;
  bf16* Vs = (bf16*)(smem + 73728);
  float* Om = (float*)smem;            // merge overlay: [128 q][68]
  float* Lm = (float*)(smem + 34816);  // merge overlay: [4 split][128 q]

  int t = threadIdx.x;
  int lane = t & 63, w = t >> 6;
  int col = lane & 31, hi = lane >> 5;
  int qg = w >> 2, split = w & 3;
  int bh = blockIdx.y;
  int b = bh >> 4, h = bh & 15;
  const bf16* Q = Qg + (size_t)bh * SEQ * DH;
  const bf16* K = Kg + (size_t)bh * SEQ * DH;
  const bf16* Vt = Vtg + (size_t)bh * DH * SEQ;
  int q0 = blockIdx.x * 128 + qg * 32;

  // Q as B-operand (already carries QSCALE): B[k=d][n=q]: lane holds
  // q=col, d = kc*16 + hi*8 + j
  bf16x8 bq[4];
#pragma unroll
  for (int kc = 0; kc < 4; ++kc)
    bq[kc] = *(const bf16x8*)&Q[(size_t)(q0 + col) * DH + kc * 16 + hi * 8];

  f32x16 oacc[2];
#pragma unroll
  for (int m = 0; m < 2; ++m)
#pragma unroll
    for (int r = 0; r < 16; ++r) oacc[m][r] = 0.f;
  float li = 0.f;

  // staging: threads [256*ss, 256*(ss+1)) stage split ss's 64-key tile
  int ss = t >> 8, st = t & 255;
  int kr = st >> 2, kcol = (st & 3) * 16;  // kr: row 0..63; kcol: 16 elems
  const bf16* kg = K + ((size_t)(ss * 512 + kr)) * DH + kcol;
  const bf16* vg = Vt + (size_t)kr * SEQ + ss * 512 + kcol;
  bf16* kl = Ks + ss * 4608 + kr * 72 + kcol;
  bf16* vl = Vs + ss * 4608 + kr * 72 + kcol;

  bf16x8 pk0 = *(const bf16x8*)kg;
  bf16x8 pk1 = *(const bf16x8*)(kg + 8);
  bf16x8 pv0 = *(const bf16x8*)vg;
  bf16x8 pv1 = *(const bf16x8*)(vg + 8);

  const bf16* Kb = Ks + split * 4608;
  const bf16* Vb = Vs + split * 4608;

  for (int it = 0; it < 8; ++it) {
    int buf = (it & 1) * 18432;  // elements
    *(bf16x8*)(kl + buf) = pk0;
    *(bf16x8*)(kl + buf + 8) = pk1;
    *(bf16x8*)(vl + buf) = pv0;
    *(bf16x8*)(vl + buf + 8) = pv1;
    __syncthreads();  // single barrier per tile (double-buffered)

    if (it + 1 < 8) {
      size_t ko = (size_t)(it + 1) * 64 * DH;
      pk0 = *(const bf16x8*)(kg + ko);
      pk1 = *(const bf16x8*)(kg + ko + 8);
      pv0 = *(const bf16x8*)(vg + (it + 1) * 64);
      pv1 = *(const bf16x8*)(vg + (it + 1) * 64 + 8);
    }
    const bf16* Kt = Kb + buf;
    const bf16* Vtb = Vb + buf;

#pragma unroll
    for (int mt = 0; mt < 2; ++mt) {
      // S^T = K.Q^T: D[m=key][n=q]; lane holds q=col,
      // key = mt*32 + (r&3) + 8*(r>>2) + 4*hi
      f32x16 s;
#pragma unroll
      for (int r = 0; r < 16; ++r) s[r] = 0.f;
#pragma unroll
      for (int kc = 0; kc < 4; ++kc) {
        bf16x8 ak = *(const bf16x8*)&Kt[(mt * 32 + col) * 72 + kc * 16 + hi * 8];
        s = __builtin_amdgcn_mfma_f32_32x32x16_bf16(ak, bq[kc], s, 0, 0, 0);
      }
#pragma unroll
      for (int cc = 0; cc < 2; ++cc) {
        // regs rb..rb+7 hold keys base + {0,1,2,3,8,9,10,11} + 4*hi
        int rb = cc * 8;
        float e0 = exp2f(s[rb + 0]), e1 = exp2f(s[rb + 1]);
        float e2 = exp2f(s[rb + 2]), e3 = exp2f(s[rb + 3]);
        float e4 = exp2f(s[rb + 4]), e5 = exp2f(s[rb + 5]);
        float e6 = exp2f(s[rb + 6]), e7 = exp2f(s[rb + 7]);
        li += ((e0 + e1) + (e2 + e3)) + ((e4 + e5) + (e6 + e7));
        // T12: pack + permlane32_swap -> PV B-operand in registers.
        // swap(lo,hi): dst lanes32-63 <- src lanes0-31 (keys 8,9 of hi=0),
        //              src lanes0-31 <- dst lanes32-63 (keys 4,5 of hi=1).
        unsigned lo0 = pk_bf16(e0, e1), lo1 = pk_bf16(e2, e3);
        unsigned h0 = pk_bf16(e4, e5), h1 = pk_bf16(e6, e7);
        uint2v r02 = __builtin_amdgcn_permlane32_swap(lo0, h0, false, false);
        uint2v r13 = __builtin_amdgcn_permlane32_swap(lo1, h1, false, false);
        uint4v uu;
        uu[0] = r02[0]; uu[1] = r13[0]; uu[2] = r02[1]; uu[3] = r13[1];
        bf16x8 pb = __builtin_bit_cast(bf16x8, uu);  // B[k=key][n=q]

        int c = mt * 2 + cc;  // 16-key chunk within tile
        // O^T += V^T.P^T: A = V^T[d][key], D[m=d][n=q]
        bf16x8 av0 = *(const bf16x8*)&Vtb[(col) * 72 + c * 16 + hi * 8];
        bf16x8 av1 = *(const bf16x8*)&Vtb[(32 + col) * 72 + c * 16 + hi * 8];
        oacc[0] = __builtin_amdgcn_mfma_f32_32x32x16_bf16(av0, pb, oacc[0], 0, 0, 0);
        oacc[1] = __builtin_amdgcn_mfma_f32_32x32x16_bf16(av1, pb, oacc[1], 0, 0, 0);
      }
    }
  }

  // ---- 4-way split-K merge (exact): O = sum O_s, l = sum l_s ----
  li += __shfl_xor(li, 32, 64);  // l(q=col) for this wave's split
  if (lane < 32) Lm[split * 128 + qg * 32 + col] = li;
  // overlay [0,36864) = Ks buf0: last read at it=6, fenced by it=7 barrier;
  // concurrent it=7 compute reads only buf1 — disjoint.

#pragma unroll 1
  for (int rs = 1; rs < 4; ++rs) {
    if (split == rs) {
#pragma unroll
      for (int m = 0; m < 2; ++m)
#pragma unroll
        for (int rr = 0; rr < 4; ++rr) {
          floatx4 v4;
#pragma unroll
          for (int j = 0; j < 4; ++j) v4[j] = oacc[m][rr * 4 + j];
          *(floatx4*)&Om[(qg * 32 + col) * 68 + m * 32 + rr * 8 + hi * 4] = v4;
        }
    }
    __syncthreads();
    if (split == 0) {
#pragma unroll
      for (int m = 0; m < 2; ++m)
#pragma unroll
        for (int rr = 0; rr < 4; ++rr) {
          floatx4 v4 =
              *(const floatx4*)&Om[(qg * 32 + col) * 68 + m * 32 + rr * 8 + hi * 4];
#pragma unroll
          for (int j = 0; j < 4; ++j) oacc[m][rr * 4 + j] += v4[j];
        }
    }
    __syncthreads();
  }
  if (split == 0) {
#pragma unroll
    for (int m = 0; m < 2; ++m)
#pragma unroll
      for (int rr = 0; rr < 4; ++rr) {
        floatx4 v4;
#pragma unroll
        for (int j = 0; j < 4; ++j) v4[j] = oacc[m][rr * 4 + j];
        *(floatx4*)&Om[(qg * 32 + col) * 68 + m * 32 + rr * 8 + hi * 4] = v4;
      }
  }
  __syncthreads();

  // coalesced readout: 128 q x 64 d, scale by 1/l, f32x4 stores
#pragma unroll
  for (int rep = 0; rep < 2; ++rep) {
    int idx = rep * 1024 + t;
    int q = idx >> 4, dc = (idx & 15) * 4;
    float lt = Lm[q] + Lm[128 + q] + Lm[256 + q] + Lm[384 + q];
    float inv = 1.0f / lt;
    floatx4 ov = *(const floatx4*)&Om[q * 68 + dc];
    ov[0] *= inv; ov[1] *= inv; ov[2] *= inv; ov[3] *= inv;
    int ns = blockIdx.x * 128 + q;
    *(floatx4*)&Og[((size_t)(b * SEQ + ns)) * EMBED + h * DH + dc] = ov;
  }
}

// ---------------------------------------------------------------------------
// ws (38 MB): q [0,4M) k [4M,8M) vt [8M,12M) wqt..wvt [12M,15M) xb [15M,19M)
// ---------------------------------------------------------------------------
extern "C" void kernel_launch(void* const* d_in, const int* in_sizes, int n_in,
                              void* d_out, int out_size, void* d_ws, size_t ws_size,
                              hipStream_t stream) {
  const int XEL = 2 * 2048 * 1024;
  const float *x, *Wq, *Wk, *Wv;
  if (in_sizes[0] == XEL) {
    x = (const float*)d_in[0];
    Wq = (const float*)d_in[1];
    Wk = (const float*)d_in[2];
    Wv = (const float*)d_in[3];
  } else {
    Wk = (const float*)d_in[0];
    Wq = (const float*)d_in[1];
    Wv = (const float*)d_in[2];
    x = (const float*)d_in[3];
  }
  bf16* ws = (bf16*)d_ws;

  const size_t M1 = 1024 * 1024;
  bf16* q_ws = ws;
  bf16* k_ws = ws + 4 * M1;
  bf16* vt_ws = ws + 8 * M1;
  bf16* wqt = ws + 12 * M1;
  bf16* wkt = ws + 13 * M1;
  bf16* wvt = ws + 14 * M1;
  bf16* xb = ws + 15 * M1;

  prep<<<dim3(256, 4), 256, 0, stream>>>(x, Wq, Wk, Wv, xb, wqt, wkt, wvt);
  qkv3<<<dim3(768), 256, 0, stream>>>(xb, wqt, wkt, wvt, q_ws, k_ws, vt_ws);
  flash<<<dim3(16, 32), 1024, 0, stream>>>(q_ws, k_ws, vt_ws, (float*)d_out);
}